// Round 20
// baseline (269.957 us; speedup 1.0000x reference)
//
#include <hip/hip_runtime.h>

// Problem constants (match reference)
#define NN    30000
#define EE    480000
#define ETOT  (EE + NN)   // edges + self-loops = 510000
#define GG    64
#define IN_CH 128
#define HID   128
#define HEADS 4
#define F1    (HEADS * HID)   // 512
#define CAP   64              // per-node edge bucket capacity (max deg ~36 for Poisson(16))

typedef __attribute__((ext_vector_type(8))) __bf16 bf16x8;
typedef __attribute__((ext_vector_type(4))) float  floatx4;
typedef __attribute__((ext_vector_type(2))) float  f32x2;

__device__ __forceinline__ float lrelu(float x) { return x > 0.f ? x : 0.2f * x; }
__device__ __forceinline__ float elu_f(float x) { return x > 0.f ? x : (expf(x) - 1.f); }
__device__ __forceinline__ unsigned short f2bf(float f) {   // round-to-nearest-even
    unsigned int u = __float_as_uint(f);
    return (unsigned short)((u + 0x7FFFu + ((u >> 16) & 1u)) >> 16);
}
__device__ __forceinline__ float bf2f(unsigned short u) {
    return __uint_as_float(((unsigned int)u) << 16);
}
__device__ __forceinline__ f32x2 fma2(float a, f32x2 v, f32x2 acc) {
    f32x2 av = {a, a};
    return __builtin_elementwise_fma(av, v, acc);   // -> v_pk_fma_f32
}

// ---------------- fused GEMM1+GEMM2, BARRIER-FREE: hh2 = elu(agg@W1+b1)@W2 -------------
// Each wave owns 32 rows end-to-end. B fragments loaded DIRECTLY global->VGPR (weights
// are L2-resident; staging them in LDS only bought barriers — R16/R18 lesson). The only
// LDS is the wave-PRIVATE out1 tile (C-layout -> A-layout transpose), wave_barrier only.
// Zero __syncthreads: waves fully independent, latency hidden by occupancy.
#define LDW 136   // padded LDS k-stride (bf16): 272B
__global__ __launch_bounds__(256) void gemm12_k(const unsigned short* __restrict__ agg,  // [NN][512]
                                                const unsigned short* __restrict__ W1t,  // [4][128n][128k]
                                                const unsigned short* __restrict__ W2t,  // [128n][512k]
                                                const float* __restrict__ b1,            // [512]
                                                unsigned short* __restrict__ hh2,        // [NN][128]
                                                const float* __restrict__ ws,
                                                const float* __restrict__ wd,
                                                float* __restrict__ as_out,
                                                float* __restrict__ ad_out,
                                                int M)
{
    __shared__ unsigned short H1c[4][32 * LDW];   // wave-private tiles, 4 x 8.7KB

    const int tid  = threadIdx.x;
    const int w    = tid >> 6, lane = tid & 63;
    const int quad = lane >> 4, l16 = lane & 15;
    const int bm   = blockIdx.x * 128 + w * 32;   // this wave's 32 rows
    unsigned short* Hw = &H1c[w][0];

    floatx4 zf = {0.f, 0.f, 0.f, 0.f};
    floatx4 acc2[2][8];
#pragma unroll
    for (int rt = 0; rt < 2; rt++)
#pragma unroll
        for (int ct = 0; ct < 8; ct++) acc2[rt][ct] = zf;

    for (int h = 0; h < 4; h++) {
        // A fragments (this wave's 32 rows, head-h k-slice)
        uint4 av[2][4];
#pragma unroll
        for (int rt = 0; rt < 2; rt++) {
            int r = bm + rt * 16 + l16;
#pragma unroll
            for (int kb = 0; kb < 4; kb++)
                av[rt][kb] = (r < M)
                    ? *(const uint4*)(agg + (size_t)r * F1 + h * 128 + kb * 32 + quad * 8)
                    : uint4{0, 0, 0, 0};
        }
        float bb[8];
#pragma unroll
        for (int ct = 0; ct < 8; ct++) bb[ct] = b1[h * 128 + ct * 16 + l16];

        // MFMA1 with direct-global B fragments (L2-hot)
        floatx4 acc1[2][8];
#pragma unroll
        for (int rt = 0; rt < 2; rt++)
#pragma unroll
            for (int ct = 0; ct < 8; ct++) acc1[rt][ct] = zf;
#pragma unroll
        for (int kb = 0; kb < 4; kb++) {
#pragma unroll
            for (int ct = 0; ct < 8; ct++) {
                bf16x8 bfr = *(const bf16x8*)(W1t + h * 16384 + (ct * 16 + l16) * 128
                                              + kb * 32 + quad * 8);
#pragma unroll
                for (int rt = 0; rt < 2; rt++) {
                    bf16x8 a = *(bf16x8*)&av[rt][kb];
                    acc1[rt][ct] = __builtin_amdgcn_mfma_f32_16x16x32_bf16(a, bfr, acc1[rt][ct], 0, 0, 0);
                }
            }
        }

        // bias+ELU+bf16 into wave-private H1c (C-layout scatter), wave-synchronous
        __builtin_amdgcn_wave_barrier();   // prev head's ds_reads retired before overwrite
#pragma unroll
        for (int rt = 0; rt < 2; rt++)
#pragma unroll
            for (int ct = 0; ct < 8; ct++)
#pragma unroll
                for (int reg = 0; reg < 4; reg++) {
                    float v = elu_f(acc1[rt][ct][reg] + bb[ct]);
                    Hw[(rt * 16 + quad * 4 + reg) * LDW + ct * 16 + l16] = f2bf(v);
                }
        __builtin_amdgcn_wave_barrier();

        // MFMA2 with direct-global W2 fragments, A from wave-private H1c
#pragma unroll
        for (int kb = 0; kb < 4; kb++) {
            bf16x8 af[2];
#pragma unroll
            for (int rt = 0; rt < 2; rt++)
                af[rt] = *(bf16x8*)&Hw[(rt * 16 + l16) * LDW + kb * 32 + quad * 8];
#pragma unroll
            for (int ct = 0; ct < 8; ct++) {
                bf16x8 bfr = *(const bf16x8*)(W2t + (size_t)(ct * 16 + l16) * F1 + h * 128
                                              + kb * 32 + quad * 8);
#pragma unroll
                for (int rt = 0; rt < 2; rt++)
                    acc2[rt][ct] = __builtin_amdgcn_mfma_f32_16x16x32_bf16(af[rt], bfr, acc2[rt][ct], 0, 0, 0);
            }
        }
    }

    // ---- wave-local epilogue: repack (stride 128) -> coalesced stores + fused scores --
    __builtin_amdgcn_wave_barrier();
#pragma unroll
    for (int rt = 0; rt < 2; rt++)
#pragma unroll
        for (int ct = 0; ct < 8; ct++)
#pragma unroll
            for (int reg = 0; reg < 4; reg++)
                Hw[(rt * 16 + quad * 4 + reg) * 128 + ct * 16 + l16] = f2bf(acc2[rt][ct][reg]);
    __builtin_amdgcn_wave_barrier();
    // wave's 32 rows x 128 cols bf16 = 512 uint4 -> 8 per lane
#pragma unroll
    for (int i = 0; i < 8; i++) {
        int j = i * 64 + lane;            // uint4 idx in [0,512)
        int rl = j >> 4, off = (j & 15) * 8;
        int row = bm + rl;
        if (row < M)
            *(uint4*)(hh2 + (size_t)row * HID + off) = *(uint4*)&Hw[rl * 128 + off];
    }
    // layer-2 attention scores for the wave's 32 rows
#pragma unroll
    for (int rt = 0; rt < 2; rt++) {
        int rl = rt * 16 + l16;
        int row = bm + rl;
        const unsigned short* rowp = &Hw[rl * 128 + quad * 32];
        float ps = 0.f, pd = 0.f;
#pragma unroll
        for (int jj = 0; jj < 32; jj++) {
            float hv = bf2f(rowp[jj]);
            ps = fmaf(hv, ws[quad * 32 + jj], ps);
            pd = fmaf(hv, wd[quad * 32 + jj], pd);
        }
        ps += __shfl_xor(ps, 16); ps += __shfl_xor(ps, 32);
        pd += __shfl_xor(pd, 16); pd += __shfl_xor(pd, 32);
        if (quad == 0 && row < M) { as_out[row] = ps; ad_out[row] = pd; }
    }
}

// ---------------- fused prep: W transposes + folded att vectors + zero deg/pooled ------
__global__ void prep_k(const float* __restrict__ W1, const float* __restrict__ W2,
                       const float* __restrict__ att_s, const float* __restrict__ att_d,
                       unsigned short* __restrict__ W1t, unsigned short* __restrict__ W2t,
                       float* __restrict__ wt, int* __restrict__ deg,
                       float* __restrict__ pooled_cnt)
{
    int b = blockIdx.x;
    if (b < 256) {                       // W1t: [h][n][k], 4*128*128
        int idx = b * 256 + threadIdx.x;
        int h = idx >> 14, rem = idx & 16383, n = rem >> 7, k = rem & 127;
        W1t[idx] = f2bf(W1[(size_t)k * F1 + h * 128 + n]);
    } else if (b < 512) {                // W2t: [n][k], 128*512
        int idx = (b - 256) * 256 + threadIdx.x;
        int n = idx >> 9, k = idx & 511;
        W2t[idx] = f2bf(W2[(size_t)k * HID + n]);
    } else if (b < 520) {                // folded att vectors: wt[2][4][128]
        if (threadIdx.x < 128) {
            int q = b - 512;             // 0..7
            int h = q & 3, sd = q >> 2;
            int i = threadIdx.x;
            const float* att = (sd ? att_d : att_s) + h * 128;
            const float* wr = W1 + (size_t)i * F1 + h * 128;
            float acc = 0.f;
            for (int c = 0; c < 128; c++) acc = fmaf(wr[c], att[c], acc);
            wt[sd * 512 + h * 128 + i] = acc;
        }
    } else if (b < 638) {                // zero deg[NN]
        int i = (b - 520) * 256 + threadIdx.x;
        if (i < NN) deg[i] = 0;
    } else {                             // zero pooled + cnt (GG*HID+GG floats)
        int i = (b - 638) * 256 + threadIdx.x;
        if (i < GG * HID + GG) pooled_cnt[i] = 0.f;
    }
}

// ---------------- fused: layer-1 scores + x->bf16 cast  ||  bucket CSR fill ------------
#define SCORE_BLKS ((NN + 31) / 32)     // 938 blocks of 32 nodes
__global__ __launch_bounds__(256) void scorefill_k(const float* __restrict__ x,
                                                   const float* __restrict__ wt,
                                                   float* __restrict__ a_s,
                                                   float* __restrict__ a_d,
                                                   unsigned short* __restrict__ x16,
                                                   const int* __restrict__ ei,
                                                   int* __restrict__ deg,
                                                   int* __restrict__ perm)
{
    int b = blockIdx.x;
    int t = threadIdx.x;
    if (b < SCORE_BLKS) {
        __shared__ __align__(16) float swt[1024];
        ((float4*)swt)[t] = ((const float4*)wt)[t];   // 256 x float4 = 1024 floats
        __syncthreads();
        const int node0 = b * 32;
        int node = node0 + (t >> 3);
        int q = t & 7;
        int h = q & 3, sd = q >> 2;
        if (node < NN) {
            const float4* xr = (const float4*)(x + (size_t)node * IN_CH);
            const float4* wr = (const float4*)(swt + sd * 512 + h * 128);
            float acc = 0.f;
#pragma unroll 4
            for (int c = 0; c < 32; c++) {
                float4 xv = xr[c], wv = wr[c];
                acc = fmaf(xv.x, wv.x, acc);
                acc = fmaf(xv.y, wv.y, acc);
                acc = fmaf(xv.z, wv.z, acc);
                acc = fmaf(xv.w, wv.w, acc);
            }
            if (sd == 0) a_s[node * 4 + h] = acc;
            else         a_d[node * 4 + h] = acc;
        }
        // cast these 32 rows to bf16 (L1-hot)
        int col = t & 127;
#pragma unroll 4
        for (int r = (t >> 7); r < 32; r += 2) {
            int nr = node0 + r;
            if (nr < NN)
                x16[(size_t)nr * IN_CH + col] = f2bf(x[(size_t)nr * IN_CH + col]);
        }
    } else {
        int i = (b - SCORE_BLKS) * 256 + t;
        if (i < ETOT) {
            int s, d;
            if (i < EE) { s = ei[i]; d = ei[EE + i]; }
            else        { s = i - EE; d = i - EE; }
            int p = atomicAdd(&deg[d], 1);
            if (p < CAP) perm[(size_t)d * CAP + p] = s;
        }
    }
}

// ---------------- layer 1: wave-per-node fused softmax+aggregate -> agg bf16 [N,4,128] -
__global__ __launch_bounds__(256) void gat_agg1w(const unsigned short* __restrict__ x16,
                                                 const float* __restrict__ a_s,
                                                 const float* __restrict__ a_d,
                                                 const int* __restrict__ deg,
                                                 const int* __restrict__ perm,
                                                 unsigned short* __restrict__ agg)
{
    __shared__ int    sSrc[4][64];
    __shared__ __align__(16) float4 sE[4][64];
    const int wave = threadIdx.x >> 6;
    const int lane = threadIdx.x & 63;
    const int hw   = lane >> 5;          // half-wave
    const int c4   = (lane & 31) * 4;    // channels c4..c4+3
    int n = blockIdx.x * 4 + wave;
    if (n >= NN) return;
    const int rem = min(deg[n], CAP);
    const float4 ad4 = *(const float4*)(a_d + (size_t)n * 4);

    if (lane < rem) {
        int sj = perm[(size_t)n * CAP + lane];
        float4 av = *(const float4*)(a_s + (size_t)sj * 4);
        sSrc[wave][lane] = sj;
        sE[wave][lane] = make_float4(__expf(lrelu(av.x + ad4.x)), __expf(lrelu(av.y + ad4.y)),
                                     __expf(lrelu(av.z + ad4.z)), __expf(lrelu(av.w + ad4.w)));
    }
    __builtin_amdgcn_wave_barrier();

    f32x2 aLo[4] = {{0,0},{0,0},{0,0},{0,0}};   // per head, channels c4,c4+1
    f32x2 aHi[4] = {{0,0},{0,0},{0,0},{0,0}};   // per head, channels c4+2,c4+3
    f32x2 den01 = {0,0}, den23 = {0,0};

    for (int j = hw; j < rem; j += 2) {
        int s = sSrc[wave][j];
        float4 ev = sE[wave][j];
        den01 += (f32x2){ev.x, ev.y};
        den23 += (f32x2){ev.z, ev.w};
        uint2 uv = *(const uint2*)(x16 + (size_t)s * IN_CH + c4);
        f32x2 xlo = { __uint_as_float(uv.x << 16), __uint_as_float(uv.x & 0xFFFF0000u) };
        f32x2 xhi = { __uint_as_float(uv.y << 16), __uint_as_float(uv.y & 0xFFFF0000u) };
        aLo[0] = fma2(ev.x, xlo, aLo[0]); aHi[0] = fma2(ev.x, xhi, aHi[0]);
        aLo[1] = fma2(ev.y, xlo, aLo[1]); aHi[1] = fma2(ev.y, xhi, aHi[1]);
        aLo[2] = fma2(ev.z, xlo, aLo[2]); aHi[2] = fma2(ev.z, xhi, aHi[2]);
        aLo[3] = fma2(ev.w, xlo, aLo[3]); aHi[3] = fma2(ev.w, xhi, aHi[3]);
    }
    // cross-half combine
#pragma unroll
    for (int h = 0; h < 4; h++) {
        aLo[h].x += __shfl_xor(aLo[h].x, 32); aLo[h].y += __shfl_xor(aLo[h].y, 32);
        aHi[h].x += __shfl_xor(aHi[h].x, 32); aHi[h].y += __shfl_xor(aHi[h].y, 32);
    }
    den01.x += __shfl_xor(den01.x, 32); den01.y += __shfl_xor(den01.y, 32);
    den23.x += __shfl_xor(den23.x, 32); den23.y += __shfl_xor(den23.y, 32);
    const float iv0 = 1.f / (den01.x + 1e-16f), iv1 = 1.f / (den01.y + 1e-16f);
    const float iv2 = 1.f / (den23.x + 1e-16f), iv3 = 1.f / (den23.y + 1e-16f);

    // write: half 0 -> heads 0,1 ; half 1 -> heads 2,3 (4 ch per lane, uint2 stores)
#pragma unroll
    for (int k = 0; k < 2; k++) {
        int h = hw * 2 + k;
        f32x2 lo = hw ? aLo[2 + k] : aLo[k];
        f32x2 hi = hw ? aHi[2 + k] : aHi[k];
        float iv = hw ? (k ? iv3 : iv2) : (k ? iv1 : iv0);
        uint2 o;
        o.x = (unsigned)f2bf(lo.x * iv) | ((unsigned)f2bf(lo.y * iv) << 16);
        o.y = (unsigned)f2bf(hi.x * iv) | ((unsigned)f2bf(hi.y * iv) << 16);
        *(uint2*)(agg + (size_t)n * F1 + h * 128 + c4) = o;
    }
}

// ---------------- layer 2: wave-per-node fused softmax+aggregate (H=1), ELU, bf16 out --
__global__ __launch_bounds__(256) void gat_agg2w(const unsigned short* __restrict__ h16,
                                                 const float* __restrict__ a_s,
                                                 const float* __restrict__ a_d,
                                                 const int* __restrict__ deg,
                                                 const int* __restrict__ perm,
                                                 const float* __restrict__ bias,
                                                 unsigned short* __restrict__ out16)
{
    int n = blockIdx.x * 4 + (threadIdx.x >> 6);
    if (n >= NN) return;
    const int lane = threadIdx.x & 63;
    const int hw   = lane >> 5;
    const int c4   = (lane & 31) * 4;
    const int rem = min(deg[n], CAP);
    const float ad = a_d[n];

    int sj = 0; float e = 0.f;
    if (lane < rem) {
        sj = perm[(size_t)n * CAP + lane];
        e = __expf(lrelu(a_s[sj] + ad));
    }
    f32x2 accLo = {0,0}, accHi = {0,0};
    float den = 0.f;
    for (int j = hw; j < rem; j += 2) {
        int   s = __shfl(sj, j);
        float a = __shfl(e, j);
        den += a;
        uint2 uv = *(const uint2*)(h16 + (size_t)s * HID + c4);
        f32x2 lo = { __uint_as_float(uv.x << 16), __uint_as_float(uv.x & 0xFFFF0000u) };
        f32x2 hi = { __uint_as_float(uv.y << 16), __uint_as_float(uv.y & 0xFFFF0000u) };
        accLo = fma2(a, lo, accLo);
        accHi = fma2(a, hi, accHi);
    }
    accLo.x += __shfl_xor(accLo.x, 32); accLo.y += __shfl_xor(accLo.y, 32);
    accHi.x += __shfl_xor(accHi.x, 32); accHi.y += __shfl_xor(accHi.y, 32);
    den += __shfl_xor(den, 32);
    const float inv = 1.f / (den + 1e-16f);
    if (hw == 0) {
        float4 bb = *(const float4*)(bias + c4);
        uint2 o;
        o.x = (unsigned)f2bf(elu_f(accLo.x * inv + bb.x)) |
              ((unsigned)f2bf(elu_f(accLo.y * inv + bb.y)) << 16);
        o.y = (unsigned)f2bf(elu_f(accHi.x * inv + bb.z)) |
              ((unsigned)f2bf(elu_f(accHi.y * inv + bb.w)) << 16);
        *(uint2*)(out16 + (size_t)n * HID + c4) = o;
    }
}

// ---------------- segmented pooling (batch is sorted), bf16 input ----------------
#define NPB 64
__global__ __launch_bounds__(128) void pool_seg_k(const unsigned short* __restrict__ out16,
                                                  const int* __restrict__ batch,
                                                  float* __restrict__ pooled,
                                                  float* __restrict__ cnt)
{
    int n0 = blockIdx.x * NPB;
    int n1 = min(n0 + NPB, NN);
    if (n0 >= n1) return;
    int t = threadIdx.x;
    int cur = batch[n0];
    float acc = 0.f;
    int count = 0;
    for (int n = n0; n < n1; n++) {
        int g = batch[n];
        if (g != cur) {
            atomicAdd(&pooled[cur * HID + t], acc);
            if (t == 0) atomicAdd(&cnt[cur], (float)count);
            acc = 0.f; count = 0; cur = g;
        }
        acc += bf2f(out16[(size_t)n * HID + t]);
        count++;
    }
    atomicAdd(&pooled[cur * HID + t], acc);
    if (t == 0) atomicAdd(&cnt[cur], (float)count);
}

__global__ void final_k(const float* __restrict__ pooled, const float* __restrict__ cnt,
                        const float* __restrict__ lw, const float* __restrict__ lb,
                        float* __restrict__ outp)
{
    int g = threadIdx.x;
    if (g < GG) {
        float acc = 0.f;
        for (int c = 0; c < HID; c++) acc += pooled[g * HID + c] * lw[c];
        float cc = fmaxf(cnt[g], 1.0f);
        outp[g] = acc / cc + lb[0];
    }
}

// ---------------- launch ----------------
extern "C" void kernel_launch(void* const* d_in, const int* in_sizes, int n_in,
                              void* d_out, int out_size, void* d_ws, size_t ws_size,
                              hipStream_t stream)
{
    const float* x    = (const float*)d_in[0];
    const int*   ei   = (const int*)d_in[1];
    const int*   batch= (const int*)d_in[2];
    const float* W1   = (const float*)d_in[3];
    const float* as1w = (const float*)d_in[4];
    const float* ad1w = (const float*)d_in[5];
    const float* b1   = (const float*)d_in[6];
    const float* W2   = (const float*)d_in[7];
    const float* as2w = (const float*)d_in[8];
    const float* ad2w = (const float*)d_in[9];
    const float* b2   = (const float*)d_in[10];
    const float* lw   = (const float*)d_in[11];
    const float* lb   = (const float*)d_in[12];
    float* outp = (float*)d_out;

    char* w = (char*)d_ws;
    size_t off = 0;
    auto alloc = [&](size_t bytes) -> char* {
        char* p = w + off;
        off += (bytes + 255) & ~(size_t)255;
        return p;
    };
    char*  reg0   = alloc((size_t)NN * F1 * 2);       // agg16 (30.7MB bf16)
    char*  reg1   = alloc((size_t)NN * HID * 2 * 2);  // hh2_16 (7.7MB) + out2_16 (7.7MB)
    unsigned short* x16 = (unsigned short*)alloc((size_t)NN * IN_CH * 2);  // 7.7MB
    unsigned short* W1t = (unsigned short*)alloc(65536 * 2);  // [4][128 n][128 k] bf16
    unsigned short* W2t = (unsigned short*)alloc(65536 * 2);  // [128 n][512 k] bf16
    float* wt1    = (float*)alloc(1024 * 4);
    float* a_s1   = (float*)alloc((size_t)NN * 4 * 4);
    float* a_d1   = (float*)alloc((size_t)NN * 4 * 4);
    float* a_s2   = (float*)alloc((size_t)NN * 4);
    float* a_d2   = (float*)alloc((size_t)NN * 4);
    int*   deg    = (int*)alloc((size_t)NN * 4);
    int*   perm   = (int*)alloc((size_t)NN * CAP * 4);   // 7.7MB bucket layout
    float* pooled = (float*)alloc((size_t)(GG * HID + GG) * 4); // pooled + cnt contiguous
    float* cnt    = pooled + GG * HID;

    unsigned short* agg16   = (unsigned short*)reg0;
    unsigned short* hh2_16  = (unsigned short*)reg1;                       // [NN][128] bf16
    unsigned short* out2_16 = (unsigned short*)reg1 + (size_t)NN * HID;    // disjoint

    // prep: W transposes (bf16), folded att vectors, zero deg + pooled/cnt
    prep_k<<<671, 256, 0, stream>>>(W1, W2, as1w, ad1w, W1t, W2t, wt1, deg, pooled);

    // fused: layer-1 scores + x cast  ||  bucket CSR fill (independent halves, one launch)
    const int FILL_BLKS = (ETOT + 255) / 256;
    scorefill_k<<<SCORE_BLKS + FILL_BLKS, 256, 0, stream>>>(x, wt1, a_s1, a_d1, x16,
                                                            ei, deg, perm);

    // layer 1 aggregate (bf16 out)
    gat_agg1w<<<(NN + 3) / 4, 256, 0, stream>>>(x16, a_s1, a_d1, deg, perm, agg16);

    // fused GEMM1+GEMM2 (+fused layer-2 scores); barrier-free, wave-owns-32-rows
    gemm12_k<<<(NN + 127) / 128, 256, 0, stream>>>(agg16, W1t, W2t, b1, hh2_16,
                                                   as2w, ad2w, a_s2, a_d2, NN);

    // layer 2 aggregate (bf16 out)
    gat_agg2w<<<(NN + 3) / 4, 256, 0, stream>>>(hh2_16, a_s2, a_d2, deg, perm, b2, out2_16);

    // pool + linear (separate launches: last-block/threadfence pattern cost 40us — R14)
    pool_seg_k<<<(NN + NPB - 1) / NPB, 128, 0, stream>>>(out2_16, batch, pooled, cnt);
    final_k<<<1, 64, 0, stream>>>(pooled, cnt, lw, lb, outp);
}

// Round 21
// 233.932 us; speedup vs baseline: 1.1540x; 1.1540x over previous
//
#include <hip/hip_runtime.h>

// Problem constants (match reference)
#define NN    30000
#define EE    480000
#define ETOT  (EE + NN)   // edges + self-loops = 510000
#define GG    64
#define IN_CH 128
#define HID   128
#define HEADS 4
#define F1    (HEADS * HID)   // 512
#define CAP   64              // per-node edge bucket capacity (max deg ~36 for Poisson(16))

typedef __attribute__((ext_vector_type(8))) __bf16 bf16x8;
typedef __attribute__((ext_vector_type(4))) float  floatx4;
typedef __attribute__((ext_vector_type(2))) float  f32x2;

__device__ __forceinline__ float lrelu(float x) { return x > 0.f ? x : 0.2f * x; }
__device__ __forceinline__ float elu_f(float x) { return x > 0.f ? x : (expf(x) - 1.f); }
__device__ __forceinline__ unsigned short f2bf(float f) {   // round-to-nearest-even
    unsigned int u = __float_as_uint(f);
    return (unsigned short)((u + 0x7FFFu + ((u >> 16) & 1u)) >> 16);
}
__device__ __forceinline__ float bf2f(unsigned short u) {
    return __uint_as_float(((unsigned int)u) << 16);
}
__device__ __forceinline__ f32x2 fma2(float a, f32x2 v, f32x2 acc) {
    f32x2 av = {a, a};
    return __builtin_elementwise_fma(av, v, acc);   // -> v_pk_fma_f32
}

// ---------------- fused GEMM1+GEMM2 (32 rows/block, best measured): ---------------------
// hh2 = elu(agg@W1+b1)@W2. Per head h: stage W1t[h] (32KB LDS) -> MFMA -> bias+ELU+bf16
// into H1c (8.7KB LDS) -> stage W2t k-slice h -> MFMA-accumulate C2. out1 never hits HBM.
// Design space explored: 32-row staged (46us, best) / 128-row staged (48us, 1 blk/CU
// latency-exposed) / barrier-free direct-global B (99us, scattered L2). Staging B in LDS
// wins because it converts scattered per-lane weight reads into one coalesced stage.
#define LDW 136   // padded LDS k-stride (bf16): 272B
__global__ __launch_bounds__(256) void gemm12_k(const unsigned short* __restrict__ agg,  // [NN][512]
                                                const unsigned short* __restrict__ W1t,  // [4][128n][128k]
                                                const unsigned short* __restrict__ W2t,  // [128n][512k]
                                                const float* __restrict__ b1,            // [512]
                                                unsigned short* __restrict__ hh2,        // [NN][128]
                                                const float* __restrict__ ws,
                                                const float* __restrict__ wd,
                                                float* __restrict__ as_out,
                                                float* __restrict__ ad_out,
                                                int M)
{
    __shared__ unsigned short Bl[128 * LDW];    // 34.8KB weight stage (reused by epilogue)
    __shared__ unsigned short H1c[32 * LDW];    // 8.7KB out1 tile (bf16)

    const int tid  = threadIdx.x;
    const int w    = tid >> 6, lane = tid & 63;
    const int quad = lane >> 4, l16 = lane & 15;
    const int bm   = blockIdx.x * 32;

    floatx4 zf = {0.f, 0.f, 0.f, 0.f};
    floatx4 acc2[2][2];
#pragma unroll
    for (int rt = 0; rt < 2; rt++)
#pragma unroll
        for (int ct = 0; ct < 2; ct++) acc2[rt][ct] = zf;

    for (int h = 0; h < 4; h++) {
        // A fragments for GEMM1: direct global loads (rows bm+rt*16+l16, head-h k-slice)
        uint4 av[2][4];
#pragma unroll
        for (int rt = 0; rt < 2; rt++) {
            int r = bm + rt * 16 + l16;
#pragma unroll
            for (int kb = 0; kb < 4; kb++)
                av[rt][kb] = (r < M)
                    ? *(const uint4*)(agg + (size_t)r * F1 + h * 128 + kb * 32 + quad * 8)
                    : uint4{0, 0, 0, 0};
        }

        __syncthreads();   // prev head's MFMA2 done reading Bl & H1c
        // stage W1t[h]: 128n x 128k
#pragma unroll
        for (int i = 0; i < 8; i++) {
            int j = i * 256 + tid;            // uint4 index, 2048 total
            int n = j >> 4, ko = (j & 15) * 8;
            *(uint4*)&Bl[n * LDW + ko] = *(const uint4*)(W1t + h * 16384 + n * 128 + ko);
        }
        __syncthreads();

        floatx4 acc1[2][2];
#pragma unroll
        for (int rt = 0; rt < 2; rt++)
#pragma unroll
            for (int ct = 0; ct < 2; ct++) acc1[rt][ct] = zf;
#pragma unroll
        for (int kb = 0; kb < 4; kb++) {
            bf16x8 bfr[2];
#pragma unroll
            for (int ct = 0; ct < 2; ct++)
                bfr[ct] = *(bf16x8*)&Bl[(w * 32 + ct * 16 + l16) * LDW + kb * 32 + quad * 8];
#pragma unroll
            for (int rt = 0; rt < 2; rt++) {
                bf16x8 a = *(bf16x8*)&av[rt][kb];
#pragma unroll
                for (int ct = 0; ct < 2; ct++)
                    acc1[rt][ct] = __builtin_amdgcn_mfma_f32_16x16x32_bf16(a, bfr[ct], acc1[rt][ct], 0, 0, 0);
            }
        }

        // bias + ELU + bf16 into H1c (C-layout scatter; 2-way max conflicts)
        float bb[2] = { b1[h * 128 + w * 32 + l16], b1[h * 128 + w * 32 + 16 + l16] };
#pragma unroll
        for (int rt = 0; rt < 2; rt++)
#pragma unroll
            for (int ct = 0; ct < 2; ct++)
#pragma unroll
                for (int reg = 0; reg < 4; reg++) {
                    float v = elu_f(acc1[rt][ct][reg] + bb[ct]);
                    H1c[(rt * 16 + quad * 4 + reg) * LDW + w * 32 + ct * 16 + l16] = f2bf(v);
                }
        __syncthreads();   // MFMA1 done reading Bl; H1c complete
        // stage W2t k-slice h: 128n x 128k (row stride 512 in W2t)
#pragma unroll
        for (int i = 0; i < 8; i++) {
            int j = i * 256 + tid;
            int n = j >> 4, ko = (j & 15) * 8;
            *(uint4*)&Bl[n * LDW + ko] = *(const uint4*)(W2t + (size_t)n * F1 + h * 128 + ko);
        }
        __syncthreads();

        // MFMA2: acc2 += H1c @ W2-slice
#pragma unroll
        for (int kb = 0; kb < 4; kb++) {
            bf16x8 af[2], bfr[2];
#pragma unroll
            for (int rt = 0; rt < 2; rt++)
                af[rt] = *(bf16x8*)&H1c[(rt * 16 + l16) * LDW + kb * 32 + quad * 8];
#pragma unroll
            for (int ct = 0; ct < 2; ct++)
                bfr[ct] = *(bf16x8*)&Bl[(w * 32 + ct * 16 + l16) * LDW + kb * 32 + quad * 8];
#pragma unroll
            for (int rt = 0; rt < 2; rt++)
#pragma unroll
                for (int ct = 0; ct < 2; ct++)
                    acc2[rt][ct] = __builtin_amdgcn_mfma_f32_16x16x32_bf16(af[rt], bfr[ct], acc2[rt][ct], 0, 0, 0);
        }
    }

    // ---- epilogue: repack (stride 128) into Bl -> coalesced stores + fused scores ----
    __syncthreads();   // MFMA2 done reading Bl
#pragma unroll
    for (int rt = 0; rt < 2; rt++)
#pragma unroll
        for (int ct = 0; ct < 2; ct++)
#pragma unroll
            for (int reg = 0; reg < 4; reg++)
                Bl[(rt * 16 + quad * 4 + reg) * 128 + w * 32 + ct * 16 + l16] =
                    f2bf(acc2[rt][ct][reg]);
    __syncthreads();
    // 32 rows x 128 cols bf16 = 512 uint4 -> 2 iterations of 256 threads
#pragma unroll
    for (int i = 0; i < 2; i++) {
        int j = i * 256 + tid;            // uint4 idx in [0,512)
        int rl = j >> 4, off = (j & 15) * 8;
        int row = bm + rl;
        if (row < M)
            *(uint4*)(hh2 + (size_t)row * HID + off) = *(uint4*)&Bl[rl * 128 + off];
    }
    // layer-2 attention scores: waves 0,1 cover rows 0..15 / 16..31
    if (w < 2) {
        int rl = w * 16 + l16;
        int row = bm + rl;
        const unsigned short* rowp = &Bl[rl * 128 + quad * 32];
        float ps = 0.f, pd = 0.f;
#pragma unroll
        for (int jj = 0; jj < 32; jj++) {
            float hv = bf2f(rowp[jj]);
            ps = fmaf(hv, ws[quad * 32 + jj], ps);
            pd = fmaf(hv, wd[quad * 32 + jj], pd);
        }
        ps += __shfl_xor(ps, 16); ps += __shfl_xor(ps, 32);
        pd += __shfl_xor(pd, 16); pd += __shfl_xor(pd, 32);
        if (quad == 0 && row < M) { as_out[row] = ps; ad_out[row] = pd; }
    }
}

// ---------------- fused prep: W transposes + folded att vectors + zero deg/pooled ------
__global__ void prep_k(const float* __restrict__ W1, const float* __restrict__ W2,
                       const float* __restrict__ att_s, const float* __restrict__ att_d,
                       unsigned short* __restrict__ W1t, unsigned short* __restrict__ W2t,
                       float* __restrict__ wt, int* __restrict__ deg,
                       float* __restrict__ pooled_cnt)
{
    int b = blockIdx.x;
    if (b < 256) {                       // W1t: [h][n][k], 4*128*128
        int idx = b * 256 + threadIdx.x;
        int h = idx >> 14, rem = idx & 16383, n = rem >> 7, k = rem & 127;
        W1t[idx] = f2bf(W1[(size_t)k * F1 + h * 128 + n]);
    } else if (b < 512) {                // W2t: [n][k], 128*512
        int idx = (b - 256) * 256 + threadIdx.x;
        int n = idx >> 9, k = idx & 511;
        W2t[idx] = f2bf(W2[(size_t)k * HID + n]);
    } else if (b < 520) {                // folded att vectors: wt[2][4][128]
        if (threadIdx.x < 128) {
            int q = b - 512;             // 0..7
            int h = q & 3, sd = q >> 2;
            int i = threadIdx.x;
            const float* att = (sd ? att_d : att_s) + h * 128;
            const float* wr = W1 + (size_t)i * F1 + h * 128;
            float acc = 0.f;
            for (int c = 0; c < 128; c++) acc = fmaf(wr[c], att[c], acc);
            wt[sd * 512 + h * 128 + i] = acc;
        }
    } else if (b < 638) {                // zero deg[NN]
        int i = (b - 520) * 256 + threadIdx.x;
        if (i < NN) deg[i] = 0;
    } else {                             // zero pooled + cnt (GG*HID+GG floats)
        int i = (b - 638) * 256 + threadIdx.x;
        if (i < GG * HID + GG) pooled_cnt[i] = 0.f;
    }
}

// ---------------- fused: layer-1 scores + x->bf16 cast  ||  bucket CSR fill ------------
#define SCORE_BLKS ((NN + 31) / 32)     // 938 blocks of 32 nodes
__global__ __launch_bounds__(256) void scorefill_k(const float* __restrict__ x,
                                                   const float* __restrict__ wt,
                                                   float* __restrict__ a_s,
                                                   float* __restrict__ a_d,
                                                   unsigned short* __restrict__ x16,
                                                   const int* __restrict__ ei,
                                                   int* __restrict__ deg,
                                                   int* __restrict__ perm)
{
    int b = blockIdx.x;
    int t = threadIdx.x;
    if (b < SCORE_BLKS) {
        __shared__ __align__(16) float swt[1024];
        ((float4*)swt)[t] = ((const float4*)wt)[t];   // 256 x float4 = 1024 floats
        __syncthreads();
        const int node0 = b * 32;
        int node = node0 + (t >> 3);
        int q = t & 7;
        int h = q & 3, sd = q >> 2;
        if (node < NN) {
            const float4* xr = (const float4*)(x + (size_t)node * IN_CH);
            const float4* wr = (const float4*)(swt + sd * 512 + h * 128);
            float acc = 0.f;
#pragma unroll 4
            for (int c = 0; c < 32; c++) {
                float4 xv = xr[c], wv = wr[c];
                acc = fmaf(xv.x, wv.x, acc);
                acc = fmaf(xv.y, wv.y, acc);
                acc = fmaf(xv.z, wv.z, acc);
                acc = fmaf(xv.w, wv.w, acc);
            }
            if (sd == 0) a_s[node * 4 + h] = acc;
            else         a_d[node * 4 + h] = acc;
        }
        // cast these 32 rows to bf16 (L1-hot)
        int col = t & 127;
#pragma unroll 4
        for (int r = (t >> 7); r < 32; r += 2) {
            int nr = node0 + r;
            if (nr < NN)
                x16[(size_t)nr * IN_CH + col] = f2bf(x[(size_t)nr * IN_CH + col]);
        }
    } else {
        int i = (b - SCORE_BLKS) * 256 + t;
        if (i < ETOT) {
            int s, d;
            if (i < EE) { s = ei[i]; d = ei[EE + i]; }
            else        { s = i - EE; d = i - EE; }
            int p = atomicAdd(&deg[d], 1);
            if (p < CAP) perm[(size_t)d * CAP + p] = s;
        }
    }
}

// ---------------- layer 1: wave-per-node fused softmax+aggregate -> agg bf16 [N,4,128] -
__global__ __launch_bounds__(256) void gat_agg1w(const unsigned short* __restrict__ x16,
                                                 const float* __restrict__ a_s,
                                                 const float* __restrict__ a_d,
                                                 const int* __restrict__ deg,
                                                 const int* __restrict__ perm,
                                                 unsigned short* __restrict__ agg)
{
    __shared__ int    sSrc[4][64];
    __shared__ __align__(16) float4 sE[4][64];
    const int wave = threadIdx.x >> 6;
    const int lane = threadIdx.x & 63;
    const int hw   = lane >> 5;          // half-wave
    const int c4   = (lane & 31) * 4;    // channels c4..c4+3
    int n = blockIdx.x * 4 + wave;
    if (n >= NN) return;
    const int rem = min(deg[n], CAP);
    const float4 ad4 = *(const float4*)(a_d + (size_t)n * 4);

    if (lane < rem) {
        int sj = perm[(size_t)n * CAP + lane];
        float4 av = *(const float4*)(a_s + (size_t)sj * 4);
        sSrc[wave][lane] = sj;
        sE[wave][lane] = make_float4(__expf(lrelu(av.x + ad4.x)), __expf(lrelu(av.y + ad4.y)),
                                     __expf(lrelu(av.z + ad4.z)), __expf(lrelu(av.w + ad4.w)));
    }
    __builtin_amdgcn_wave_barrier();

    f32x2 aLo[4] = {{0,0},{0,0},{0,0},{0,0}};   // per head, channels c4,c4+1
    f32x2 aHi[4] = {{0,0},{0,0},{0,0},{0,0}};   // per head, channels c4+2,c4+3
    f32x2 den01 = {0,0}, den23 = {0,0};

    for (int j = hw; j < rem; j += 2) {
        int s = sSrc[wave][j];
        float4 ev = sE[wave][j];
        den01 += (f32x2){ev.x, ev.y};
        den23 += (f32x2){ev.z, ev.w};
        uint2 uv = *(const uint2*)(x16 + (size_t)s * IN_CH + c4);
        f32x2 xlo = { __uint_as_float(uv.x << 16), __uint_as_float(uv.x & 0xFFFF0000u) };
        f32x2 xhi = { __uint_as_float(uv.y << 16), __uint_as_float(uv.y & 0xFFFF0000u) };
        aLo[0] = fma2(ev.x, xlo, aLo[0]); aHi[0] = fma2(ev.x, xhi, aHi[0]);
        aLo[1] = fma2(ev.y, xlo, aLo[1]); aHi[1] = fma2(ev.y, xhi, aHi[1]);
        aLo[2] = fma2(ev.z, xlo, aLo[2]); aHi[2] = fma2(ev.z, xhi, aHi[2]);
        aLo[3] = fma2(ev.w, xlo, aLo[3]); aHi[3] = fma2(ev.w, xhi, aHi[3]);
    }
    // cross-half combine
#pragma unroll
    for (int h = 0; h < 4; h++) {
        aLo[h].x += __shfl_xor(aLo[h].x, 32); aLo[h].y += __shfl_xor(aLo[h].y, 32);
        aHi[h].x += __shfl_xor(aHi[h].x, 32); aHi[h].y += __shfl_xor(aHi[h].y, 32);
    }
    den01.x += __shfl_xor(den01.x, 32); den01.y += __shfl_xor(den01.y, 32);
    den23.x += __shfl_xor(den23.x, 32); den23.y += __shfl_xor(den23.y, 32);
    const float iv0 = 1.f / (den01.x + 1e-16f), iv1 = 1.f / (den01.y + 1e-16f);
    const float iv2 = 1.f / (den23.x + 1e-16f), iv3 = 1.f / (den23.y + 1e-16f);

    // write: half 0 -> heads 0,1 ; half 1 -> heads 2,3 (4 ch per lane, uint2 stores)
#pragma unroll
    for (int k = 0; k < 2; k++) {
        int h = hw * 2 + k;
        f32x2 lo = hw ? aLo[2 + k] : aLo[k];
        f32x2 hi = hw ? aHi[2 + k] : aHi[k];
        float iv = hw ? (k ? iv3 : iv2) : (k ? iv1 : iv0);
        uint2 o;
        o.x = (unsigned)f2bf(lo.x * iv) | ((unsigned)f2bf(lo.y * iv) << 16);
        o.y = (unsigned)f2bf(hi.x * iv) | ((unsigned)f2bf(hi.y * iv) << 16);
        *(uint2*)(agg + (size_t)n * F1 + h * 128 + c4) = o;
    }
}

// ---------------- layer 2: wave-per-node fused softmax+aggregate (H=1), ELU, bf16 out --
__global__ __launch_bounds__(256) void gat_agg2w(const unsigned short* __restrict__ h16,
                                                 const float* __restrict__ a_s,
                                                 const float* __restrict__ a_d,
                                                 const int* __restrict__ deg,
                                                 const int* __restrict__ perm,
                                                 const float* __restrict__ bias,
                                                 unsigned short* __restrict__ out16)
{
    int n = blockIdx.x * 4 + (threadIdx.x >> 6);
    if (n >= NN) return;
    const int lane = threadIdx.x & 63;
    const int hw   = lane >> 5;
    const int c4   = (lane & 31) * 4;
    const int rem = min(deg[n], CAP);
    const float ad = a_d[n];

    int sj = 0; float e = 0.f;
    if (lane < rem) {
        sj = perm[(size_t)n * CAP + lane];
        e = __expf(lrelu(a_s[sj] + ad));
    }
    f32x2 accLo = {0,0}, accHi = {0,0};
    float den = 0.f;
    for (int j = hw; j < rem; j += 2) {
        int   s = __shfl(sj, j);
        float a = __shfl(e, j);
        den += a;
        uint2 uv = *(const uint2*)(h16 + (size_t)s * HID + c4);
        f32x2 lo = { __uint_as_float(uv.x << 16), __uint_as_float(uv.x & 0xFFFF0000u) };
        f32x2 hi = { __uint_as_float(uv.y << 16), __uint_as_float(uv.y & 0xFFFF0000u) };
        accLo = fma2(a, lo, accLo);
        accHi = fma2(a, hi, accHi);
    }
    accLo.x += __shfl_xor(accLo.x, 32); accLo.y += __shfl_xor(accLo.y, 32);
    accHi.x += __shfl_xor(accHi.x, 32); accHi.y += __shfl_xor(accHi.y, 32);
    den += __shfl_xor(den, 32);
    const float inv = 1.f / (den + 1e-16f);
    if (hw == 0) {
        float4 bb = *(const float4*)(bias + c4);
        uint2 o;
        o.x = (unsigned)f2bf(elu_f(accLo.x * inv + bb.x)) |
              ((unsigned)f2bf(elu_f(accLo.y * inv + bb.y)) << 16);
        o.y = (unsigned)f2bf(elu_f(accHi.x * inv + bb.z)) |
              ((unsigned)f2bf(elu_f(accHi.y * inv + bb.w)) << 16);
        *(uint2*)(out16 + (size_t)n * HID + c4) = o;
    }
}

// ---------------- segmented pooling (batch is sorted), bf16 input ----------------
#define NPB 64
__global__ __launch_bounds__(128) void pool_seg_k(const unsigned short* __restrict__ out16,
                                                  const int* __restrict__ batch,
                                                  float* __restrict__ pooled,
                                                  float* __restrict__ cnt)
{
    int n0 = blockIdx.x * NPB;
    int n1 = min(n0 + NPB, NN);
    if (n0 >= n1) return;
    int t = threadIdx.x;
    int cur = batch[n0];
    float acc = 0.f;
    int count = 0;
    for (int n = n0; n < n1; n++) {
        int g = batch[n];
        if (g != cur) {
            atomicAdd(&pooled[cur * HID + t], acc);
            if (t == 0) atomicAdd(&cnt[cur], (float)count);
            acc = 0.f; count = 0; cur = g;
        }
        acc += bf2f(out16[(size_t)n * HID + t]);
        count++;
    }
    atomicAdd(&pooled[cur * HID + t], acc);
    if (t == 0) atomicAdd(&cnt[cur], (float)count);
}

__global__ void final_k(const float* __restrict__ pooled, const float* __restrict__ cnt,
                        const float* __restrict__ lw, const float* __restrict__ lb,
                        float* __restrict__ outp)
{
    int g = threadIdx.x;
    if (g < GG) {
        float acc = 0.f;
        for (int c = 0; c < HID; c++) acc += pooled[g * HID + c] * lw[c];
        float cc = fmaxf(cnt[g], 1.0f);
        outp[g] = acc / cc + lb[0];
    }
}

// ---------------- launch ----------------
extern "C" void kernel_launch(void* const* d_in, const int* in_sizes, int n_in,
                              void* d_out, int out_size, void* d_ws, size_t ws_size,
                              hipStream_t stream)
{
    const float* x    = (const float*)d_in[0];
    const int*   ei   = (const int*)d_in[1];
    const int*   batch= (const int*)d_in[2];
    const float* W1   = (const float*)d_in[3];
    const float* as1w = (const float*)d_in[4];
    const float* ad1w = (const float*)d_in[5];
    const float* b1   = (const float*)d_in[6];
    const float* W2   = (const float*)d_in[7];
    const float* as2w = (const float*)d_in[8];
    const float* ad2w = (const float*)d_in[9];
    const float* b2   = (const float*)d_in[10];
    const float* lw   = (const float*)d_in[11];
    const float* lb   = (const float*)d_in[12];
    float* outp = (float*)d_out;

    char* w = (char*)d_ws;
    size_t off = 0;
    auto alloc = [&](size_t bytes) -> char* {
        char* p = w + off;
        off += (bytes + 255) & ~(size_t)255;
        return p;
    };
    char*  reg0   = alloc((size_t)NN * F1 * 2);       // agg16 (30.7MB bf16)
    char*  reg1   = alloc((size_t)NN * HID * 2 * 2);  // hh2_16 (7.7MB) + out2_16 (7.7MB)
    unsigned short* x16 = (unsigned short*)alloc((size_t)NN * IN_CH * 2);  // 7.7MB
    unsigned short* W1t = (unsigned short*)alloc(65536 * 2);  // [4][128 n][128 k] bf16
    unsigned short* W2t = (unsigned short*)alloc(65536 * 2);  // [128 n][512 k] bf16
    float* wt1    = (float*)alloc(1024 * 4);
    float* a_s1   = (float*)alloc((size_t)NN * 4 * 4);
    float* a_d1   = (float*)alloc((size_t)NN * 4 * 4);
    float* a_s2   = (float*)alloc((size_t)NN * 4);
    float* a_d2   = (float*)alloc((size_t)NN * 4);
    int*   deg    = (int*)alloc((size_t)NN * 4);
    int*   perm   = (int*)alloc((size_t)NN * CAP * 4);   // 7.7MB bucket layout
    float* pooled = (float*)alloc((size_t)(GG * HID + GG) * 4); // pooled + cnt contiguous
    float* cnt    = pooled + GG * HID;

    unsigned short* agg16   = (unsigned short*)reg0;
    unsigned short* hh2_16  = (unsigned short*)reg1;                       // [NN][128] bf16
    unsigned short* out2_16 = (unsigned short*)reg1 + (size_t)NN * HID;    // disjoint

    // prep: W transposes (bf16), folded att vectors, zero deg + pooled/cnt
    prep_k<<<671, 256, 0, stream>>>(W1, W2, as1w, ad1w, W1t, W2t, wt1, deg, pooled);

    // fused: layer-1 scores + x cast  ||  bucket CSR fill (independent halves, one launch)
    const int FILL_BLKS = (ETOT + 255) / 256;
    scorefill_k<<<SCORE_BLKS + FILL_BLKS, 256, 0, stream>>>(x, wt1, a_s1, a_d1, x16,
                                                            ei, deg, perm);

    // layer 1 aggregate (bf16 out)
    gat_agg1w<<<(NN + 3) / 4, 256, 0, stream>>>(x16, a_s1, a_d1, deg, perm, agg16);

    // fused GEMM1+GEMM2 (+fused layer-2 scores); 32 rows/block (best measured config)
    gemm12_k<<<(NN + 31) / 32, 256, 0, stream>>>(agg16, W1t, W2t, b1, hh2_16,
                                                 as2w, ad2w, a_s2, a_d2, NN);

    // layer 2 aggregate (bf16 out)
    gat_agg2w<<<(NN + 3) / 4, 256, 0, stream>>>(hh2_16, a_s2, a_d2, deg, perm, b2, out2_16);

    // pool + linear (separate launches: last-block/threadfence pattern cost 40us — R14)
    pool_seg_k<<<(NN + NPB - 1) / NPB, 128, 0, stream>>>(out2_16, batch, pooled, cnt);
    final_k<<<1, 64, 0, stream>>>(pooled, cnt, lw, lb, outp);
}